// Round 3
// baseline (10451.921 us; speedup 1.0000x reference)
//
#include <hip/hip_runtime.h>
#include <hip/hip_bf16.h>

// Problem dims
#define BB   32      // batch
#define NN   98      // image regions
#define EE   2048    // img feature dim
#define HH   512     // hidden
#define VV   10000   // vocab
#define TT   60      // timesteps (T_CAP-1)
#define TCAP 61
#define GG   256     // megakernel grid (1 block/CU guaranteed co-resident)

typedef unsigned short u16;
typedef __attribute__((ext_vector_type(8))) short bh8;
typedef __attribute__((ext_vector_type(4))) float f32x4;

__device__ __forceinline__ float bsf(unsigned s) {
    union { unsigned u; float f; } w; w.u = s << 16; return w.f;
}
__device__ __forceinline__ u16 f2bu(float f) {
    union { float f; unsigned u; } v; v.f = f;
    unsigned u = v.u;
    u = u + 0x7fffu + ((u >> 16) & 1u);   // RNE
    return (u16)(u >> 16);
}
__device__ __forceinline__ bh8 ld8(const u16* p) {
    return *reinterpret_cast<const bh8*>(p);
}
__device__ __forceinline__ float sigm(float x) {
    return __builtin_amdgcn_rcpf(1.0f + exp2f(-1.4426950408889634f * x));
}
__device__ __forceinline__ float tanh_(float x) {
    return 1.0f - 2.0f * __builtin_amdgcn_rcpf(1.0f + exp2f(2.885390081777927f * x));
}

// Grid barrier: monotonic counter, release/acquire via __threadfence (agent scope
// -> L2 writeback+inv on gfx95x, required for cross-XCD visibility).
__device__ __forceinline__ void gbar(unsigned* bar, unsigned target) {
    __threadfence();                       // release: my writes reach coherence point
    __syncthreads();
    if (threadIdx.x == 0) {
        atomicAdd(bar, 1u);
        while (__hip_atomic_load(bar, __ATOMIC_RELAXED, __HIP_MEMORY_SCOPE_AGENT) < target)
            __builtin_amdgcn_s_sleep(1);
    }
    __syncthreads();
    __threadfence();                       // acquire: invalidate stale cache lines
}

__global__ __launch_bounds__(64) void k_zero(unsigned* bar) {
    if (threadIdx.x == 0) *bar = 0u;
}

// ---------------- k_conv: fp32 -> bf16 elementwise (n multiple of 1024) -------
__global__ __launch_bounds__(256) void k_conv(
    const float* __restrict__ src, u16* __restrict__ dst)
{
    int i = blockIdx.x * 256 + threadIdx.x;
    float4 v = reinterpret_cast<const float4*>(src)[i];
    ushort4 o;
    o.x = f2bu(v.x); o.y = f2bu(v.y); o.z = f2bu(v.z); o.w = f2bu(v.w);
    reinterpret_cast<ushort4*>(dst)[i] = o;
}

// ---------------- init1: avg features (fp32) + scaled embedding gather --------
__global__ __launch_bounds__(256) void k_init1(
    const float* __restrict__ img, const int* __restrict__ caps,
    const float* __restrict__ emb, u16* __restrict__ avg_bf, u16* __restrict__ emb_all)
{
    int bid = blockIdx.x, tid = threadIdx.x;
    if (bid < 256) {
        int b = bid >> 3, et = bid & 7;
        int ec = et * 256 + tid;
        const float* p = img + (size_t)(b * NN) * EE + ec;
        float s = 0.f;
        for (int n = 0; n < NN; ++n) s += p[(size_t)n * EE];
        avg_bf[b * EE + ec] = f2bu(s * (1.0f / 98.0f));
    } else {
        int eb = bid - 256;                  // 240 blocks x 8 rows = 1920 rows
        for (int r8 = 0; r8 < 8; ++r8) {
            int row = eb * 8 + r8;           // row = t*32 + b
            int t = row >> 5, b = row & 31;
            int cap = caps[b * TCAP + t];
            const float* src = emb + (size_t)cap * HH;
            u16* dst = emb_all + (size_t)row * HH;
            for (int c = tid; c < HH; c += 256)
                dst[c] = f2bu(src[c] * 22.627416997969522f);  // sqrt(512)
        }
    }
}

// ---------------- init2: h0 = tanh(avg@W_init_h.T+b), c0 likewise (MFMA) ------
__global__ __launch_bounds__(256) void k_init2(
    const u16* __restrict__ avg_bf,
    const u16* __restrict__ Wh_bf, const float* __restrict__ b_h,
    const u16* __restrict__ Wc_bf, const float* __restrict__ b_c,
    u16* __restrict__ h_all, float* __restrict__ c_ws)
{
    __shared__ float red[4][2][64][4];
    int ot = blockIdx.x, tid = threadIdx.x;       // 64 blocks x 16 outputs (1024 total)
    int w = tid >> 6, lane = tid & 63, quad = lane >> 4, l16 = lane & 15;
    int o = ot * 16 + l16;
    const u16* wrow = (o < HH) ? (Wh_bf + (size_t)o * EE) : (Wc_bf + (size_t)(o - HH) * EE);
    f32x4 acc[2]; acc[0] = {0,0,0,0}; acc[1] = {0,0,0,0};
    for (int c = w * 16; c < w * 16 + 16; ++c) {
        int k = c * 32 + quad * 8;
        bh8 b8 = ld8(wrow + k);
        for (int mt = 0; mt < 2; ++mt) {
            bh8 a8 = ld8(avg_bf + (size_t)(mt * 16 + l16) * EE + k);
            acc[mt] = __builtin_amdgcn_mfma_f32_16x16x32_bf16(a8, b8, acc[mt], 0, 0, 0);
        }
    }
    for (int mt = 0; mt < 2; ++mt)
        for (int r = 0; r < 4; ++r) red[w][mt][lane][r] = acc[mt][r];
    __syncthreads();
    for (int idx = tid; idx < 512; idx += 256) {
        int mg = idx >> 4, nn2 = idx & 15;
        int mt = mg >> 4, m = mg & 15;
        int sl = nn2 + 16 * (m >> 2), rg = m & 3;
        float v = red[0][mt][sl][rg] + red[1][mt][sl][rg] + red[2][mt][sl][rg] + red[3][mt][sl][rg];
        int oo = ot * 16 + nn2, b = mg;
        if (oo < HH)
            h_all[(size_t)b * HH + oo] = f2bu(tanh_(v + b_h[oo]));     // h_all[0]
        else
            c_ws[b * HH + (oo - HH)] = tanh_(v + b_c[oo - HH]);
    }
}

// ---------------- Ws = img @ W_att.T + b_att (MFMA, one-shot) -----------------
__global__ __launch_bounds__(256) void k_ws(
    const u16* __restrict__ img_bf, const u16* __restrict__ Watt_bf,
    const float* __restrict__ b_att, u16* __restrict__ Ws_bf)
{
    int bid = blockIdx.x, tid = threadIdx.x;      // 49 mt x 16 nt = 784 blocks
    int mt = bid >> 4, nt = bid & 15;
    int w = tid >> 6, lane = tid & 63, quad = lane >> 4, l16 = lane & 15;
    int rowA = mt * 64 + w * 16 + l16;            // bn index < 3136
    f32x4 acc[2]; acc[0] = {0,0,0,0}; acc[1] = {0,0,0,0};
    const u16* arow = img_bf + (size_t)rowA * EE;
    for (int c = 0; c < 64; ++c) {
        int k = c * 32 + quad * 8;
        bh8 a8 = ld8(arow + k);
        for (int s = 0; s < 2; ++s) {
            bh8 b8 = ld8(Watt_bf + (size_t)(nt * 32 + s * 16 + l16) * EE + k);
            acc[s] = __builtin_amdgcn_mfma_f32_16x16x32_bf16(a8, b8, acc[s], 0, 0, 0);
        }
    }
    for (int s = 0; s < 2; ++s)
        for (int r = 0; r < 4; ++r) {
            int m = quad * 4 + r;
            int row = mt * 64 + w * 16 + m;
            int col = nt * 32 + s * 16 + l16;
            Ws_bf[(size_t)row * HH + col] = f2bu(acc[s][r] + b_att[col]);
        }
}

// ======================= Megakernel phases ====================================

// Phase A (g<160): Wu = h@W_U.T + b_U ; gate = sigm(h@W_fb.T + b_fb)
__device__ __forceinline__ void phaseA(float* sm, int g, int t,
    const u16* h_all, const u16* __restrict__ WU_bf, const float* __restrict__ b_U,
    const u16* __restrict__ Wfb_bf, const float* __restrict__ b_fb,
    float* Wu_ws, float* gate_ws)
{
    int tid = threadIdx.x;
    int w = tid >> 6, lane = tid & 63, quad = lane >> 4, l16 = lane & 15;
    int o = g * 16 + l16;
    const u16* wrow = (o < HH) ? (WU_bf + (size_t)o * HH) : (Wfb_bf + (size_t)(o - HH) * HH);
    const u16* hbase = h_all + (size_t)t * BB * HH;
    f32x4 acc[2]; acc[0] = {0,0,0,0}; acc[1] = {0,0,0,0};
    for (int c = w * 4; c < w * 4 + 4; ++c) {
        int k = c * 32 + quad * 8;
        bh8 b8 = ld8(wrow + k);
        for (int mt = 0; mt < 2; ++mt) {
            bh8 a8 = ld8(hbase + (size_t)(mt * 16 + l16) * HH + k);
            acc[mt] = __builtin_amdgcn_mfma_f32_16x16x32_bf16(a8, b8, acc[mt], 0, 0, 0);
        }
    }
    for (int mt = 0; mt < 2; ++mt)
        for (int r = 0; r < 4; ++r)
            sm[(((w * 2 + mt) * 64) + lane) * 4 + r] = acc[mt][r];
    __syncthreads();
    for (int idx = tid; idx < 512; idx += 256) {
        int mg = idx >> 4, nn2 = idx & 15;
        int mt = mg >> 4, m = mg & 15;
        int sl = nn2 + 16 * (m >> 2), rg = m & 3;
        float v = sm[(((0 * 2 + mt) * 64) + sl) * 4 + rg]
                + sm[(((1 * 2 + mt) * 64) + sl) * 4 + rg]
                + sm[(((2 * 2 + mt) * 64) + sl) * 4 + rg]
                + sm[(((3 * 2 + mt) * 64) + sl) * 4 + rg];
        int oo = g * 16 + nn2, b = mg;
        if (oo < HH)
            Wu_ws[b * HH + oo] = v + b_U[oo];
        else
            gate_ws[b * EE + (oo - HH)] = sigm(v + b_fb[oo - HH]);
    }
}

// Phase B (g<128): e = Wv.tanh(Ws+Wu)+bv ; softmax ; xctx = gate * (alpha.img)
__device__ __forceinline__ void phaseB(float* sm, int g,
    const u16* __restrict__ img_bf, const u16* __restrict__ Ws_bf,
    const float* Wu_ws, const float* gate_ws,
    const float* __restrict__ W_v, const float* __restrict__ b_v,
    u16* xctx)
{
    float* e_sh = sm;            // [98]
    float* a_sh = sm + 128;      // [98]
    int tid = threadIdx.x;
    int b = g >> 2, et = g & 3;
    int w = tid >> 6, lane = tid & 63;
    float wu[8], wv[8];
    {
        const float* wup = Wu_ws + b * HH + lane * 8;
        const float* wvp = W_v + lane * 8;
        #pragma unroll
        for (int j = 0; j < 8; ++j) { wu[j] = wup[j]; wv[j] = wvp[j]; }
    }
    for (int n = w; n < NN; n += 4) {
        bh8 ws8 = ld8(Ws_bf + (size_t)(b * NN + n) * HH + lane * 8);
        float acc = 0.f;
        #pragma unroll
        for (int j = 0; j < 8; ++j) acc += wv[j] * tanh_(bsf((u16)ws8[j]) + wu[j]);
        #pragma unroll
        for (int off = 32; off > 0; off >>= 1) acc += __shfl_down(acc, off, 64);
        if (lane == 0) e_sh[n] = acc + b_v[0];
    }
    __syncthreads();
    if (tid < 64) {
        float e0 = e_sh[tid];
        float e1 = (tid + 64 < NN) ? e_sh[tid + 64] : -1e30f;
        float m = fmaxf(e0, e1);
        #pragma unroll
        for (int off = 32; off > 0; off >>= 1) m = fmaxf(m, __shfl_xor(m, off, 64));
        const float L2E = 1.4426950408889634f;
        float x0 = exp2f((e0 - m) * L2E);
        float x1 = (tid + 64 < NN) ? exp2f((e1 - m) * L2E) : 0.f;
        float s = x0 + x1;
        #pragma unroll
        for (int off = 32; off > 0; off >>= 1) s += __shfl_xor(s, off, 64);
        float inv = __builtin_amdgcn_rcpf(s);
        a_sh[tid] = x0 * inv;
        if (tid + 64 < NN) a_sh[tid + 64] = x1 * inv;
    }
    __syncthreads();
    int ec = et * 512 + tid * 2;
    const u16* ip = img_bf + (size_t)b * NN * EE + ec;
    float c0 = 0.f, c1 = 0.f;
    for (int n = 0; n < NN; ++n) {
        unsigned u = *reinterpret_cast<const unsigned*>(ip + (size_t)n * EE);
        float a = a_sh[n];
        c0 = fmaf(a, bsf(u & 0xffffu), c0);
        c1 = fmaf(a, bsf(u >> 16), c1);
    }
    float g0 = gate_ws[b * EE + ec], g1 = gate_ws[b * EE + ec + 1];
    unsigned outw = ((unsigned)f2bu(g1 * c1) << 16) | (unsigned)f2bu(g0 * c0);
    *reinterpret_cast<unsigned*>(xctx + (size_t)b * EE + ec) = outw;
}

// Phase C (all 256): gates GEMM (K=3072 concat) + LSTM update -> h[t+1], c
__device__ __forceinline__ void phaseC(float* sm, int g, int t,
    const u16* __restrict__ emb_all, const u16* xctx, u16* h_all,
    const u16* __restrict__ Wih_bf, const float* __restrict__ b_ih,
    const u16* __restrict__ Whh_bf, const float* __restrict__ b_hh,
    float* c_ws)
{
    float* red = sm;              // [4][64][4]
    float* gsh = sm + 1024;       // [16][16]
    int tid = threadIdx.x;
    int kt = g & 127, mt = g >> 7;
    int w = tid >> 6, lane = tid & 63, quad = lane >> 4, l16 = lane & 15;
    int brow = mt * 16 + l16;
    int j = kt * 4 + (l16 & 3) + HH * (l16 >> 2);  // gate row: k + 512*gate
    const u16* embrow = emb_all + (size_t)(t * BB + brow) * HH;
    const u16* xrow   = xctx + (size_t)brow * EE;
    const u16* hrow   = h_all + (size_t)(t * BB + brow) * HH;
    const u16* wih    = Wih_bf + (size_t)j * (HH + EE);
    const u16* whh    = Whh_bf + (size_t)j * HH;
    f32x4 acc = {0,0,0,0};
    for (int c = w * 24; c < w * 24 + 24; ++c) {   // waves split K: 96 chunks of 32
        int k = c * 32 + quad * 8;
        bh8 a8, b8;
        if (c < 16)      a8 = ld8(embrow + k);
        else if (c < 80) a8 = ld8(xrow + (k - HH));
        else             a8 = ld8(hrow + (k - HH - EE));
        if (c < 80)      b8 = ld8(wih + k);
        else             b8 = ld8(whh + (k - HH - EE));
        acc = __builtin_amdgcn_mfma_f32_16x16x32_bf16(a8, b8, acc, 0, 0, 0);
    }
    for (int r = 0; r < 4; ++r) red[(w * 64 + lane) * 4 + r] = acc[r];
    __syncthreads();
    {
        int m = tid >> 4, nn2 = tid & 15;
        int sl = nn2 + 16 * (m >> 2), rg = m & 3;
        int jj = kt * 4 + (nn2 & 3) + HH * (nn2 >> 2);
        float v = red[(0 * 64 + sl) * 4 + rg] + red[(1 * 64 + sl) * 4 + rg]
                + red[(2 * 64 + sl) * 4 + rg] + red[(3 * 64 + sl) * 4 + rg]
                + b_ih[jj] + b_hh[jj];
        gsh[m * 16 + nn2] = v;
    }
    __syncthreads();
    if (tid < 64) {
        int m = tid >> 2, i = tid & 3;
        int b = mt * 16 + m, k = kt * 4 + i;
        float gi = gsh[m * 16 + i], gf = gsh[m * 16 + i + 4];
        float gg = gsh[m * 16 + i + 8], go = gsh[m * 16 + i + 12];
        float cold = c_ws[b * HH + k];
        float c2 = sigm(gf) * cold + sigm(gi) * tanh_(gg);
        float h2 = sigm(go) * tanh_(c2);
        c_ws[b * HH + k] = c2;
        h_all[(size_t)((t + 1) * BB + b) * HH + k] = f2bu(h2);
    }
}

__global__ __launch_bounds__(256) void k_mega(
    const u16* __restrict__ img_bf, const u16* __restrict__ Ws_bf,
    const u16* __restrict__ emb_all,
    u16* h_all, float* c_ws, float* Wu_ws, float* gate_ws, u16* xctx,
    const u16* __restrict__ WU_bf, const float* __restrict__ b_U,
    const u16* __restrict__ Wfb_bf, const float* __restrict__ b_fb,
    const float* __restrict__ W_v, const float* __restrict__ b_v,
    const u16* __restrict__ Wih_bf, const float* __restrict__ b_ih,
    const u16* __restrict__ Whh_bf, const float* __restrict__ b_hh,
    unsigned* bar)
{
    __shared__ float sm[2048];
    int g = blockIdx.x;
    unsigned tgt = 0;
    for (int t = 0; t < TT; ++t) {
        if (g < 160) phaseA(sm, g, t, h_all, WU_bf, b_U, Wfb_bf, b_fb, Wu_ws, gate_ws);
        tgt += GG; gbar(bar, tgt);
        if (g < 128) phaseB(sm, g, img_bf, Ws_bf, Wu_ws, gate_ws, W_v, b_v, xctx);
        tgt += GG; gbar(bar, tgt);
        phaseC(sm, g, t, emb_all, xctx, h_all, Wih_bf, b_ih, Whh_bf, b_hh, c_ws);
        if (t < TT - 1) { tgt += GG; gbar(bar, tgt); }
    }
}

// ---------------- k_pred: all-step pred = h2 @ W_out.T + b_out (MFMA) ---------
__global__ __launch_bounds__(256) void k_pred(
    const u16* __restrict__ h_all, const u16* __restrict__ Wout_bf,
    const float* __restrict__ b_out, float* __restrict__ out)
{
    int bid = blockIdx.x, tid = threadIdx.x;       // 15 mt(128 rows) x 79 vt(128 v)
    int mt = bid / 79, vt = bid % 79;
    int w = tid >> 6, lane = tid & 63, quad = lane >> 4, l16 = lane & 15;
    f32x4 acc[8][2];
    for (int mi = 0; mi < 8; ++mi) for (int s = 0; s < 2; ++s) acc[mi][s] = {0,0,0,0};
    int nact[2]; int vbase[2];
    for (int s = 0; s < 2; ++s) {
        int ntg = vt * 8 + 2 * w + s;               // 625 total 16-wide v-tiles
        nact[s] = (ntg < 625);
        vbase[s] = ntg * 16;
    }
    for (int c = 0; c < 16; ++c) {
        int k = c * 32 + quad * 8;
        bh8 b8[2];
        for (int s = 0; s < 2; ++s) if (nact[s])
            b8[s] = ld8(Wout_bf + (size_t)(vbase[s] + l16) * HH + k);
        for (int mi = 0; mi < 8; ++mi) {
            int row = 32 + mt * 128 + mi * 16 + l16;   // h2 rows (skip h0 block)
            bh8 a8 = ld8(h_all + (size_t)row * HH + k);
            for (int s = 0; s < 2; ++s) if (nact[s])
                acc[mi][s] = __builtin_amdgcn_mfma_f32_16x16x32_bf16(a8, b8[s], acc[mi][s], 0, 0, 0);
        }
    }
    for (int s = 0; s < 2; ++s) if (nact[s]) {
        int v = vbase[s] + l16;
        float bo = b_out[v];
        for (int mi = 0; mi < 8; ++mi)
            for (int r = 0; r < 4; ++r) {
                int row = 32 + mt * 128 + mi * 16 + quad * 4 + r;
                int tt = (row >> 5) - 1, b = row & 31;
                __builtin_nontemporal_store(acc[mi][s][r] + bo,
                                            &out[(size_t)(b * TT + tt) * VV + v]);
            }
    }
}

extern "C" void kernel_launch(void* const* d_in, const int* in_sizes, int n_in,
                              void* d_out, int out_size, void* d_ws, size_t ws_size,
                              hipStream_t stream)
{
    const float* img      = (const float*)d_in[0];
    const int*   caps     = (const int*)d_in[1];
    const float* emb      = (const float*)d_in[2];
    const float* W_init_h = (const float*)d_in[3];
    const float* b_init_h = (const float*)d_in[4];
    const float* W_init_c = (const float*)d_in[5];
    const float* b_init_c = (const float*)d_in[6];
    const float* W_U      = (const float*)d_in[7];
    const float* b_U      = (const float*)d_in[8];
    const float* W_att    = (const float*)d_in[9];
    const float* b_att    = (const float*)d_in[10];
    const float* W_v      = (const float*)d_in[11];
    const float* b_v      = (const float*)d_in[12];
    const float* W_fb     = (const float*)d_in[13];
    const float* b_fb     = (const float*)d_in[14];
    const float* W_ih     = (const float*)d_in[15];
    const float* b_ih     = (const float*)d_in[16];
    const float* W_hh     = (const float*)d_in[17];
    const float* b_hh     = (const float*)d_in[18];
    const float* W_out    = (const float*)d_in[19];
    const float* b_out    = (const float*)d_in[20];
    float* out = (float*)d_out;

    char* ws = (char*)d_ws;
    u16*   img_bf  = (u16*)(ws);                    // 12,845,056 B
    u16*   Watt_bf = (u16*)(ws + 12845056);         //  2,097,152 B
    u16*   Winh_bf = (u16*)(ws + 14942208);         //  2,097,152 B
    u16*   Winc_bf = (u16*)(ws + 17039360);         //  2,097,152 B
    u16*   WU_bf   = (u16*)(ws + 19136512);         //    524,288 B
    u16*   Wfb_bf  = (u16*)(ws + 19660800);         //  2,097,152 B
    u16*   Wih_bf  = (u16*)(ws + 21757952);         // 10,485,760 B
    u16*   Whh_bf  = (u16*)(ws + 32243712);         //  2,097,152 B
    u16*   Wout_bf = (u16*)(ws + 34340864);         // 10,240,000 B
    u16*   Ws_bf   = (u16*)(ws + 44580864);         //  3,211,264 B
    u16*   emb_all = (u16*)(ws + 47792128);         //  1,966,080 B
    u16*   h_all   = (u16*)(ws + 49758208);         //  1,998,848 B
    u16*   xctx    = (u16*)(ws + 51757056);         //    131,072 B
    u16*   avg_bf  = (u16*)(ws + 51888128);         //    131,072 B
    float* c_ws    = (float*)(ws + 52019200);       //     65,536 B
    float* Wu_ws   = (float*)(ws + 52084736);       //     65,536 B
    float* gate_ws = (float*)(ws + 52150272);       //    262,144 B
    unsigned* bar  = (unsigned*)(ws + 52412416);    //        128 B
    // total ws usage: 52,412,544 bytes

    // fp32 -> bf16 conversions (grid = n/1024)
    k_conv<<<6272, 256, 0, stream>>>(img,      img_bf);
    k_conv<<<1024, 256, 0, stream>>>(W_att,    Watt_bf);
    k_conv<<<1024, 256, 0, stream>>>(W_init_h, Winh_bf);
    k_conv<<<1024, 256, 0, stream>>>(W_init_c, Winc_bf);
    k_conv<<< 256, 256, 0, stream>>>(W_U,      WU_bf);
    k_conv<<<1024, 256, 0, stream>>>(W_fb,     Wfb_bf);
    k_conv<<<5120, 256, 0, stream>>>(W_ih,     Wih_bf);
    k_conv<<<1024, 256, 0, stream>>>(W_hh,     Whh_bf);
    k_conv<<<5000, 256, 0, stream>>>(W_out,    Wout_bf);
    k_zero<<<1, 64, 0, stream>>>(bar);

    k_init1<<<496, 256, 0, stream>>>(img, caps, emb, avg_bf, emb_all);
    k_init2<<<64, 256, 0, stream>>>(avg_bf, Winh_bf, b_init_h, Winc_bf, b_init_c, h_all, c_ws);
    k_ws<<<784, 256, 0, stream>>>(img_bf, Watt_bf, b_att, Ws_bf);

    k_mega<<<GG, 256, 0, stream>>>(img_bf, Ws_bf, emb_all,
                                   h_all, c_ws, Wu_ws, gate_ws, xctx,
                                   WU_bf, b_U, Wfb_bf, b_fb, W_v, b_v,
                                   Wih_bf, b_ih, Whh_bf, b_hh, bar);

    k_pred<<<1185, 256, 0, stream>>>(h_all, Wout_bf, b_out, out);
}

// Round 4
// 3906.463 us; speedup vs baseline: 2.6755x; 2.6755x over previous
//
#include <hip/hip_runtime.h>
#include <hip/hip_bf16.h>

// Problem dims
#define BB   32      // batch
#define NN   98      // image regions
#define EE   2048    // img feature dim
#define HH   512     // hidden
#define VV   10000   // vocab
#define TT   60      // timesteps (T_CAP-1)
#define TCAP 61
#define GG   256     // megakernel grid (1 block/CU guaranteed co-resident)

typedef unsigned short u16;
typedef unsigned long long u64;
typedef __attribute__((ext_vector_type(8))) short bh8;
typedef __attribute__((ext_vector_type(4))) float f32x4;

__device__ __forceinline__ float bsf(unsigned s) {
    union { unsigned u; float f; } w; w.u = s << 16; return w.f;
}
__device__ __forceinline__ u16 f2bu(float f) {
    union { float f; unsigned u; } v; v.f = f;
    unsigned u = v.u;
    u = u + 0x7fffu + ((u >> 16) & 1u);   // RNE
    return (u16)(u >> 16);
}
__device__ __forceinline__ bh8 ld8(const u16* p) {
    return *reinterpret_cast<const bh8*>(p);
}
__device__ __forceinline__ float sigm(float x) {
    return __builtin_amdgcn_rcpf(1.0f + exp2f(-1.4426950408889634f * x));
}
__device__ __forceinline__ float tanh_(float x) {
    return 1.0f - 2.0f * __builtin_amdgcn_rcpf(1.0f + exp2f(2.885390081777927f * x));
}

// ---- coherence-point (sc1) accessors: bypass per-XCD L2, leave weights cached
#define AGT __HIP_MEMORY_SCOPE_AGENT
__device__ __forceinline__ void  stf(float* p, float v)    { __hip_atomic_store(p, v, __ATOMIC_RELAXED, AGT); }
__device__ __forceinline__ float ldf(const float* p)       { return __hip_atomic_load(p, __ATOMIC_RELAXED, AGT); }
__device__ __forceinline__ void  stu(unsigned* p, unsigned v) { __hip_atomic_store(p, v, __ATOMIC_RELAXED, AGT); }
__device__ __forceinline__ bh8 ld8_sc(const u16* p) {
    union { u64 q[2]; bh8 v; } u;
    u.q[0] = __hip_atomic_load((const u64*)p,     __ATOMIC_RELAXED, AGT);
    u.q[1] = __hip_atomic_load(((const u64*)p)+1, __ATOMIC_RELAXED, AGT);
    return u.v;
}

// Grid barrier, NO cache-flushing fences: __syncthreads drains vmcnt(0) (sc1
// stores then sit at the coherence point); consumers use sc1 loads, so no
// L2 invalidate is needed. Weights stay L2-resident across all 60 steps.
__device__ __forceinline__ void gbar(unsigned* bar, unsigned target) {
    __syncthreads();
    if (threadIdx.x == 0) {
        __hip_atomic_fetch_add(bar, 1u, __ATOMIC_RELAXED, AGT);
        while (__hip_atomic_load(bar, __ATOMIC_RELAXED, AGT) < target)
            __builtin_amdgcn_s_sleep(2);
    }
    __syncthreads();
}

// ---------------- k_pre1: all fp32->bf16 conversions + init1 + bar zero -------
// conv block offsets (1024 el per block):
//  img 0..6272 | Watt ..7296 | Winh ..8320 | Winc ..9344 | WU ..9600 |
//  Wfb ..10624 | Wih ..15744 | Whh ..16768 | Wout ..21768 | init1 ..22264
__global__ __launch_bounds__(256) void k_pre1(
    const float* __restrict__ img,      u16* __restrict__ img_bf,
    const float* __restrict__ W_att,    u16* __restrict__ Watt_bf,
    const float* __restrict__ W_init_h, u16* __restrict__ Winh_bf,
    const float* __restrict__ W_init_c, u16* __restrict__ Winc_bf,
    const float* __restrict__ W_U,      u16* __restrict__ WU_bf,
    const float* __restrict__ W_fb,     u16* __restrict__ Wfb_bf,
    const float* __restrict__ W_ih,     u16* __restrict__ Wih_bf,
    const float* __restrict__ W_hh,     u16* __restrict__ Whh_bf,
    const float* __restrict__ W_out,    u16* __restrict__ Wout_bf,
    const int* __restrict__ caps, const float* __restrict__ emb,
    u16* __restrict__ avg_bf, u16* __restrict__ emb_all, unsigned* bar)
{
    int bid = blockIdx.x, tid = threadIdx.x;
    if (bid == 0 && tid == 0) *bar = 0u;
    if (bid < 21768) {
        const float* s; u16* d; int off;
        if      (bid <  6272) { s = img;      d = img_bf;  off = 0; }
        else if (bid <  7296) { s = W_att;    d = Watt_bf; off = 6272; }
        else if (bid <  8320) { s = W_init_h; d = Winh_bf; off = 7296; }
        else if (bid <  9344) { s = W_init_c; d = Winc_bf; off = 8320; }
        else if (bid <  9600) { s = W_U;      d = WU_bf;   off = 9344; }
        else if (bid < 10624) { s = W_fb;     d = Wfb_bf;  off = 9600; }
        else if (bid < 15744) { s = W_ih;     d = Wih_bf;  off = 10624; }
        else if (bid < 16768) { s = W_hh;     d = Whh_bf;  off = 15744; }
        else                  { s = W_out;    d = Wout_bf; off = 16768; }
        int i = (bid - off) * 256 + tid;
        float4 v = reinterpret_cast<const float4*>(s)[i];
        ushort4 o;
        o.x = f2bu(v.x); o.y = f2bu(v.y); o.z = f2bu(v.z); o.w = f2bu(v.w);
        reinterpret_cast<ushort4*>(d)[i] = o;
    } else {
        int b2 = bid - 21768;                // 496 blocks: init1
        if (b2 < 256) {
            int b = b2 >> 3, et = b2 & 7;
            int ec = et * 256 + tid;
            const float* p = img + (size_t)(b * NN) * EE + ec;
            float s = 0.f;
            for (int n = 0; n < NN; ++n) s += p[(size_t)n * EE];
            avg_bf[b * EE + ec] = f2bu(s * (1.0f / 98.0f));
        } else {
            int eb = b2 - 256;               // 240 blocks x 8 rows = 1920 rows
            for (int r8 = 0; r8 < 8; ++r8) {
                int row = eb * 8 + r8;       // row = t*32 + b
                int t = row >> 5, b = row & 31;
                int cap = caps[b * TCAP + t];
                const float* src = emb + (size_t)cap * HH;
                u16* dst = emb_all + (size_t)row * HH;
                for (int c = tid; c < HH; c += 256)
                    dst[c] = f2bu(src[c] * 22.627416997969522f);  // sqrt(512)
            }
        }
    }
}

// ---------------- k_pre2: init2 (h0/c0, blocks 0..63) + Ws GEMM (64..847) -----
__global__ __launch_bounds__(256) void k_pre2(
    const u16* __restrict__ avg_bf,
    const u16* __restrict__ Wh_bf, const float* __restrict__ b_h,
    const u16* __restrict__ Wc_bf, const float* __restrict__ b_c,
    u16* __restrict__ h_all, float* __restrict__ c_ws,
    const u16* __restrict__ img_bf, const u16* __restrict__ Watt_bf,
    const float* __restrict__ b_att, u16* __restrict__ Ws_bf)
{
    __shared__ float red[4][2][64][4];
    int bid = blockIdx.x, tid = threadIdx.x;
    int w = tid >> 6, lane = tid & 63, quad = lane >> 4, l16 = lane & 15;
    if (bid < 64) {
        int ot = bid;
        int o = ot * 16 + l16;
        const u16* wrow = (o < HH) ? (Wh_bf + (size_t)o * EE) : (Wc_bf + (size_t)(o - HH) * EE);
        f32x4 acc[2]; acc[0] = {0,0,0,0}; acc[1] = {0,0,0,0};
        for (int c = w * 16; c < w * 16 + 16; ++c) {
            int k = c * 32 + quad * 8;
            bh8 b8 = ld8(wrow + k);
            for (int mt = 0; mt < 2; ++mt) {
                bh8 a8 = ld8(avg_bf + (size_t)(mt * 16 + l16) * EE + k);
                acc[mt] = __builtin_amdgcn_mfma_f32_16x16x32_bf16(a8, b8, acc[mt], 0, 0, 0);
            }
        }
        for (int mt = 0; mt < 2; ++mt)
            for (int r = 0; r < 4; ++r) red[w][mt][lane][r] = acc[mt][r];
        __syncthreads();
        for (int idx = tid; idx < 512; idx += 256) {
            int mg = idx >> 4, nn2 = idx & 15;
            int mt = mg >> 4, m = mg & 15;
            int sl = nn2 + 16 * (m >> 2), rg = m & 3;
            float v = red[0][mt][sl][rg] + red[1][mt][sl][rg] + red[2][mt][sl][rg] + red[3][mt][sl][rg];
            int oo = ot * 16 + nn2, b = mg;
            if (oo < HH)
                h_all[(size_t)b * HH + oo] = f2bu(tanh_(v + b_h[oo]));
            else
                c_ws[b * HH + (oo - HH)] = tanh_(v + b_c[oo - HH]);
        }
    } else {
        int g = bid - 64;                    // 49 mt x 16 nt = 784 blocks
        int mt = g >> 4, nt = g & 15;
        int rowA = mt * 64 + w * 16 + l16;   // bn index < 3136
        f32x4 acc[2]; acc[0] = {0,0,0,0}; acc[1] = {0,0,0,0};
        const u16* arow = img_bf + (size_t)rowA * EE;
        for (int c = 0; c < 64; ++c) {
            int k = c * 32 + quad * 8;
            bh8 a8 = ld8(arow + k);
            for (int s = 0; s < 2; ++s) {
                bh8 b8 = ld8(Watt_bf + (size_t)(nt * 32 + s * 16 + l16) * EE + k);
                acc[s] = __builtin_amdgcn_mfma_f32_16x16x32_bf16(a8, b8, acc[s], 0, 0, 0);
            }
        }
        for (int s = 0; s < 2; ++s)
            for (int r = 0; r < 4; ++r) {
                int m = quad * 4 + r;
                int row = mt * 64 + w * 16 + m;
                int col = nt * 32 + s * 16 + l16;
                Ws_bf[(size_t)row * HH + col] = f2bu(acc[s][r] + b_att[col]);
            }
    }
}

// ======================= Megakernel phases ====================================

// Phase A (g<160): Wu = h@W_U.T + b_U ; gate = sigm(h@W_fb.T + b_fb)
__device__ __forceinline__ void phaseA(float* sm, int g, int t,
    const u16* h_all, const u16* __restrict__ WU_bf, const float* __restrict__ b_U,
    const u16* __restrict__ Wfb_bf, const float* __restrict__ b_fb,
    float* Wu_ws, float* gate_ws)
{
    int tid = threadIdx.x;
    int w = tid >> 6, lane = tid & 63, quad = lane >> 4, l16 = lane & 15;
    int o = g * 16 + l16;
    const u16* wrow = (o < HH) ? (WU_bf + (size_t)o * HH) : (Wfb_bf + (size_t)(o - HH) * HH);
    const u16* hbase = h_all + (size_t)t * BB * HH;
    f32x4 acc[2]; acc[0] = {0,0,0,0}; acc[1] = {0,0,0,0};
    for (int c = w * 4; c < w * 4 + 4; ++c) {
        int k = c * 32 + quad * 8;
        bh8 b8 = ld8(wrow + k);            // weights: normal cached (L2-resident)
        for (int mt = 0; mt < 2; ++mt) {
            bh8 a8 = ld8_sc(hbase + (size_t)(mt * 16 + l16) * HH + k);  // h: sc1
            acc[mt] = __builtin_amdgcn_mfma_f32_16x16x32_bf16(a8, b8, acc[mt], 0, 0, 0);
        }
    }
    for (int mt = 0; mt < 2; ++mt)
        for (int r = 0; r < 4; ++r)
            sm[(((w * 2 + mt) * 64) + lane) * 4 + r] = acc[mt][r];
    __syncthreads();
    for (int idx = tid; idx < 512; idx += 256) {
        int mg = idx >> 4, nn2 = idx & 15;
        int mt = mg >> 4, m = mg & 15;
        int sl = nn2 + 16 * (m >> 2), rg = m & 3;
        float v = sm[(((0 * 2 + mt) * 64) + sl) * 4 + rg]
                + sm[(((1 * 2 + mt) * 64) + sl) * 4 + rg]
                + sm[(((2 * 2 + mt) * 64) + sl) * 4 + rg]
                + sm[(((3 * 2 + mt) * 64) + sl) * 4 + rg];
        int oo = g * 16 + nn2, b = mg;
        if (oo < HH)
            stf(&Wu_ws[b * HH + oo], v + b_U[oo]);
        else
            stf(&gate_ws[b * EE + (oo - HH)], sigm(v + b_fb[oo - HH]));
    }
}

// Phase B (g<128): e = Wv.tanh(Ws+Wu)+bv ; softmax ; xctx = gate * (alpha.img)
__device__ __forceinline__ void phaseB(float* sm, int g,
    const u16* __restrict__ img_bf, const u16* __restrict__ Ws_bf,
    const float* Wu_ws, const float* gate_ws,
    const float* __restrict__ W_v, const float* __restrict__ b_v,
    u16* xctx)
{
    float* e_sh = sm;            // [98]
    float* a_sh = sm + 128;      // [98]
    int tid = threadIdx.x;
    int b = g >> 2, et = g & 3;
    int w = tid >> 6, lane = tid & 63;
    float wu[8], wv[8];
    {
        const float* wup = Wu_ws + b * HH + lane * 8;
        const float* wvp = W_v + lane * 8;
        #pragma unroll
        for (int j = 0; j < 8; ++j) { wu[j] = ldf(wup + j); wv[j] = wvp[j]; }
    }
    for (int n = w; n < NN; n += 4) {
        bh8 ws8 = ld8(Ws_bf + (size_t)(b * NN + n) * HH + lane * 8);
        float acc = 0.f;
        #pragma unroll
        for (int j = 0; j < 8; ++j) acc += wv[j] * tanh_(bsf((u16)ws8[j]) + wu[j]);
        #pragma unroll
        for (int off = 32; off > 0; off >>= 1) acc += __shfl_down(acc, off, 64);
        if (lane == 0) e_sh[n] = acc + b_v[0];
    }
    __syncthreads();
    if (tid < 64) {
        float e0 = e_sh[tid];
        float e1 = (tid + 64 < NN) ? e_sh[tid + 64] : -1e30f;
        float m = fmaxf(e0, e1);
        #pragma unroll
        for (int off = 32; off > 0; off >>= 1) m = fmaxf(m, __shfl_xor(m, off, 64));
        const float L2E = 1.4426950408889634f;
        float x0 = exp2f((e0 - m) * L2E);
        float x1 = (tid + 64 < NN) ? exp2f((e1 - m) * L2E) : 0.f;
        float s = x0 + x1;
        #pragma unroll
        for (int off = 32; off > 0; off >>= 1) s += __shfl_xor(s, off, 64);
        float inv = __builtin_amdgcn_rcpf(s);
        a_sh[tid] = x0 * inv;
        if (tid + 64 < NN) a_sh[tid + 64] = x1 * inv;
    }
    __syncthreads();
    int ec = et * 512 + tid * 2;
    const u16* ip = img_bf + (size_t)b * NN * EE + ec;   // read-only: normal cached
    float c0 = 0.f, c1 = 0.f;
    for (int n = 0; n < NN; ++n) {
        unsigned u = *reinterpret_cast<const unsigned*>(ip + (size_t)n * EE);
        float a = a_sh[n];
        c0 = fmaf(a, bsf(u & 0xffffu), c0);
        c1 = fmaf(a, bsf(u >> 16), c1);
    }
    float g0 = ldf(&gate_ws[b * EE + ec]), g1 = ldf(&gate_ws[b * EE + ec + 1]);
    unsigned outw = ((unsigned)f2bu(g1 * c1) << 16) | (unsigned)f2bu(g0 * c0);
    stu(reinterpret_cast<unsigned*>(xctx + (size_t)b * EE + ec), outw);
}

// Phase C (all 256): gates GEMM (K=3072 concat) + LSTM update -> h[t+1], c
__device__ __forceinline__ void phaseC(float* sm, int g, int t,
    const u16* __restrict__ emb_all, const u16* xctx, u16* h_all,
    const u16* __restrict__ Wih_bf, const float* __restrict__ b_ih,
    const u16* __restrict__ Whh_bf, const float* __restrict__ b_hh,
    float* c_ws)
{
    float* red = sm;              // [4][64][4]
    float* gsh = sm + 1024;       // [16][16]
    int tid = threadIdx.x;
    int kt = g & 127, mt = g >> 7;
    int w = tid >> 6, lane = tid & 63, quad = lane >> 4, l16 = lane & 15;
    int brow = mt * 16 + l16;
    int j = kt * 4 + (l16 & 3) + HH * (l16 >> 2);  // gate row: k + 512*gate
    const u16* embrow = emb_all + (size_t)(t * BB + brow) * HH;
    const u16* xrow   = xctx + (size_t)brow * EE;
    const u16* hrow   = h_all + (size_t)(t * BB + brow) * HH;
    const u16* wih    = Wih_bf + (size_t)j * (HH + EE);
    const u16* whh    = Whh_bf + (size_t)j * HH;
    f32x4 acc = {0,0,0,0};
    for (int c = w * 24; c < w * 24 + 24; ++c) {   // waves split K: 96 chunks of 32
        int k = c * 32 + quad * 8;
        bh8 a8, b8;
        if (c < 16)      a8 = ld8(embrow + k);              // precomputed: cached
        else if (c < 80) a8 = ld8_sc(xrow + (k - HH));      // cross-block: sc1
        else             a8 = ld8_sc(hrow + (k - HH - EE)); // cross-block: sc1
        if (c < 80)      b8 = ld8(wih + k);                 // weights: cached
        else             b8 = ld8(whh + (k - HH - EE));
        acc = __builtin_amdgcn_mfma_f32_16x16x32_bf16(a8, b8, acc, 0, 0, 0);
    }
    for (int r = 0; r < 4; ++r) red[(w * 64 + lane) * 4 + r] = acc[r];
    __syncthreads();
    {
        int m = tid >> 4, nn2 = tid & 15;
        int sl = nn2 + 16 * (m >> 2), rg = m & 3;
        int jj = kt * 4 + (nn2 & 3) + HH * (nn2 >> 2);
        float v = red[(0 * 64 + sl) * 4 + rg] + red[(1 * 64 + sl) * 4 + rg]
                + red[(2 * 64 + sl) * 4 + rg] + red[(3 * 64 + sl) * 4 + rg]
                + b_ih[jj] + b_hh[jj];
        gsh[m * 16 + nn2] = v;
    }
    __syncthreads();
    if (tid < 64) {
        int m = tid >> 2, i = tid & 3;
        int b = mt * 16 + m, k = kt * 4 + i;
        float gi = gsh[m * 16 + i], gf = gsh[m * 16 + i + 4];
        float gg = gsh[m * 16 + i + 8], go = gsh[m * 16 + i + 12];
        float cold = c_ws[b * HH + k];                 // block-private: normal
        float c2 = sigm(gf) * cold + sigm(gi) * tanh_(gg);
        float h2 = sigm(go) * tanh_(c2);
        c_ws[b * HH + k] = c2;
        float h2n = __shfl_down(h2, 1, 64);            // pack pairs -> u32 sc1 store
        if ((i & 1) == 0) {
            unsigned pw = ((unsigned)f2bu(h2n) << 16) | (unsigned)f2bu(h2);
            stu(reinterpret_cast<unsigned*>(&h_all[(size_t)((t + 1) * BB + b) * HH + k]), pw);
        }
    }
}

__global__ __launch_bounds__(256) void k_mega(
    const u16* __restrict__ img_bf, const u16* __restrict__ Ws_bf,
    const u16* __restrict__ emb_all,
    u16* h_all, float* c_ws, float* Wu_ws, float* gate_ws, u16* xctx,
    const u16* __restrict__ WU_bf, const float* __restrict__ b_U,
    const u16* __restrict__ Wfb_bf, const float* __restrict__ b_fb,
    const float* __restrict__ W_v, const float* __restrict__ b_v,
    const u16* __restrict__ Wih_bf, const float* __restrict__ b_ih,
    const u16* __restrict__ Whh_bf, const float* __restrict__ b_hh,
    unsigned* bar)
{
    __shared__ float sm[2048];
    int g = blockIdx.x;
    unsigned tgt = 0;
    for (int t = 0; t < TT; ++t) {
        if (g < 160) phaseA(sm, g, t, h_all, WU_bf, b_U, Wfb_bf, b_fb, Wu_ws, gate_ws);
        tgt += GG; gbar(bar, tgt);
        if (g < 128) phaseB(sm, g, img_bf, Ws_bf, Wu_ws, gate_ws, W_v, b_v, xctx);
        tgt += GG; gbar(bar, tgt);
        phaseC(sm, g, t, emb_all, xctx, h_all, Wih_bf, b_ih, Whh_bf, b_hh, c_ws);
        if (t < TT - 1) { tgt += GG; gbar(bar, tgt); }
    }
}

// ---------------- k_pred: all-step pred = h2 @ W_out.T + b_out (MFMA) ---------
__global__ __launch_bounds__(256) void k_pred(
    const u16* __restrict__ h_all, const u16* __restrict__ Wout_bf,
    const float* __restrict__ b_out, float* __restrict__ out)
{
    int bid = blockIdx.x, tid = threadIdx.x;       // 15 mt(128 rows) x 79 vt(128 v)
    int mt = bid / 79, vt = bid % 79;
    int w = tid >> 6, lane = tid & 63, quad = lane >> 4, l16 = lane & 15;
    f32x4 acc[8][2];
    for (int mi = 0; mi < 8; ++mi) for (int s = 0; s < 2; ++s) acc[mi][s] = {0,0,0,0};
    int nact[2]; int vbase[2];
    for (int s = 0; s < 2; ++s) {
        int ntg = vt * 8 + 2 * w + s;               // 625 total 16-wide v-tiles
        nact[s] = (ntg < 625);
        vbase[s] = ntg * 16;
    }
    for (int c = 0; c < 16; ++c) {
        int k = c * 32 + quad * 8;
        bh8 b8[2];
        for (int s = 0; s < 2; ++s) if (nact[s])
            b8[s] = ld8(Wout_bf + (size_t)(vbase[s] + l16) * HH + k);
        for (int mi = 0; mi < 8; ++mi) {
            int row = 32 + mt * 128 + mi * 16 + l16;   // h2 rows (skip h0 block)
            bh8 a8 = ld8(h_all + (size_t)row * HH + k);
            for (int s = 0; s < 2; ++s) if (nact[s])
                acc[mi][s] = __builtin_amdgcn_mfma_f32_16x16x32_bf16(a8, b8[s], acc[mi][s], 0, 0, 0);
        }
    }
    for (int s = 0; s < 2; ++s) if (nact[s]) {
        int v = vbase[s] + l16;
        float bo = b_out[v];
        for (int mi = 0; mi < 8; ++mi)
            for (int r = 0; r < 4; ++r) {
                int row = 32 + mt * 128 + mi * 16 + quad * 4 + r;
                int tt = (row >> 5) - 1, b = row & 31;
                __builtin_nontemporal_store(acc[mi][s][r] + bo,
                                            &out[(size_t)(b * TT + tt) * VV + v]);
            }
    }
}

extern "C" void kernel_launch(void* const* d_in, const int* in_sizes, int n_in,
                              void* d_out, int out_size, void* d_ws, size_t ws_size,
                              hipStream_t stream)
{
    const float* img      = (const float*)d_in[0];
    const int*   caps     = (const int*)d_in[1];
    const float* emb      = (const float*)d_in[2];
    const float* W_init_h = (const float*)d_in[3];
    const float* b_init_h = (const float*)d_in[4];
    const float* W_init_c = (const float*)d_in[5];
    const float* b_init_c = (const float*)d_in[6];
    const float* W_U      = (const float*)d_in[7];
    const float* b_U      = (const float*)d_in[8];
    const float* W_att    = (const float*)d_in[9];
    const float* b_att    = (const float*)d_in[10];
    const float* W_v      = (const float*)d_in[11];
    const float* b_v      = (const float*)d_in[12];
    const float* W_fb     = (const float*)d_in[13];
    const float* b_fb     = (const float*)d_in[14];
    const float* W_ih     = (const float*)d_in[15];
    const float* b_ih     = (const float*)d_in[16];
    const float* W_hh     = (const float*)d_in[17];
    const float* b_hh     = (const float*)d_in[18];
    const float* W_out    = (const float*)d_in[19];
    const float* b_out    = (const float*)d_in[20];
    float* out = (float*)d_out;

    char* ws = (char*)d_ws;
    u16*   img_bf  = (u16*)(ws);                    // 12,845,056 B
    u16*   Watt_bf = (u16*)(ws + 12845056);         //  2,097,152 B
    u16*   Winh_bf = (u16*)(ws + 14942208);         //  2,097,152 B
    u16*   Winc_bf = (u16*)(ws + 17039360);         //  2,097,152 B
    u16*   WU_bf   = (u16*)(ws + 19136512);         //    524,288 B
    u16*   Wfb_bf  = (u16*)(ws + 19660800);         //  2,097,152 B
    u16*   Wih_bf  = (u16*)(ws + 21757952);         // 10,485,760 B
    u16*   Whh_bf  = (u16*)(ws + 32243712);         //  2,097,152 B
    u16*   Wout_bf = (u16*)(ws + 34340864);         // 10,240,000 B
    u16*   Ws_bf   = (u16*)(ws + 44580864);         //  3,211,264 B
    u16*   emb_all = (u16*)(ws + 47792128);         //  1,966,080 B
    u16*   h_all   = (u16*)(ws + 49758208);         //  1,998,848 B
    u16*   xctx    = (u16*)(ws + 51757056);         //    131,072 B
    u16*   avg_bf  = (u16*)(ws + 51888128);         //    131,072 B
    float* c_ws    = (float*)(ws + 52019200);       //     65,536 B
    float* Wu_ws   = (float*)(ws + 52084736);       //     65,536 B
    float* gate_ws = (float*)(ws + 52150272);       //    262,144 B
    unsigned* bar  = (unsigned*)(ws + 52412416);    //        128 B
    // total ws usage: 52,412,544 bytes

    k_pre1<<<22264, 256, 0, stream>>>(img, img_bf, W_att, Watt_bf,
                                      W_init_h, Winh_bf, W_init_c, Winc_bf,
                                      W_U, WU_bf, W_fb, Wfb_bf, W_ih, Wih_bf,
                                      W_hh, Whh_bf, W_out, Wout_bf,
                                      caps, emb, avg_bf, emb_all, bar);
    k_pre2<<<848, 256, 0, stream>>>(avg_bf, Winh_bf, b_init_h, Winc_bf, b_init_c,
                                    h_all, c_ws, img_bf, Watt_bf, b_att, Ws_bf);
    k_mega<<<GG, 256, 0, stream>>>(img_bf, Ws_bf, emb_all,
                                   h_all, c_ws, Wu_ws, gate_ws, xctx,
                                   WU_bf, b_U, Wfb_bf, b_fb, W_v, b_v,
                                   Wih_bf, b_ih, Whh_bf, b_hh, bar);
    k_pred<<<1185, 256, 0, stream>>>(h_all, Wout_bf, b_out, out);
}